// Round 10
// baseline (25422.119 us; speedup 1.0000x reference)
//
#include <hip/hip_runtime.h>

#define T_DIM 512
#define B_DIM 256
#define S_DIMS 64
#define A_DIMS 16
#define E_DIM 128
#define H_DIM 512
#define X_DIM 384   // 3*E
#define G_DIM 1536  // 3*H

typedef __attribute__((ext_vector_type(8))) short short8;
typedef __attribute__((ext_vector_type(4))) float f32x4;
typedef __attribute__((ext_vector_type(4))) unsigned uint4v;

#define MFMA16(a, b, c) __builtin_amdgcn_mfma_f32_16x16x32_bf16(a, b, c, 0, 0, 0)

__device__ __forceinline__ float gelu_tanh(float x) {
    const float c = 0.7978845608028654f; // sqrt(2/pi)
    float x3 = x * x * x;
    return 0.5f * x * (1.0f + tanhf(c * (x + 0.044715f * x3)));
}

__device__ __forceinline__ float sigmoidf(float x) {
    return 1.0f / (1.0f + expf(-x));
}

// round-to-nearest-even fp32 -> bf16 (as ushort)
__device__ __forceinline__ unsigned short f2bf(float x) {
    unsigned u = __float_as_uint(x);
    u += 0x7FFFu + ((u >> 16) & 1u);
    return (unsigned short)(u >> 16);
}
__device__ __forceinline__ float bf2f(unsigned short b) {
    return __uint_as_float(((unsigned)b) << 16);
}

// ---- system-scope (LLC-coherent, L2-bypassing) accessors: no cache flushes needed
__device__ __forceinline__ short8 ld_sys16(const unsigned short* p) {
    unsigned* q = (unsigned*)p;
    uint4v u;
    u.x = __hip_atomic_load(q + 0, __ATOMIC_RELAXED, __HIP_MEMORY_SCOPE_SYSTEM);
    u.y = __hip_atomic_load(q + 1, __ATOMIC_RELAXED, __HIP_MEMORY_SCOPE_SYSTEM);
    u.z = __hip_atomic_load(q + 2, __ATOMIC_RELAXED, __HIP_MEMORY_SCOPE_SYSTEM);
    u.w = __hip_atomic_load(q + 3, __ATOMIC_RELAXED, __HIP_MEMORY_SCOPE_SYSTEM);
    return __builtin_bit_cast(short8, u);
}
__device__ __forceinline__ float ld_sysf(const float* p) {
    return __hip_atomic_load((float*)p, __ATOMIC_RELAXED, __HIP_MEMORY_SCOPE_SYSTEM);
}
__device__ __forceinline__ void st_sysf(float* p, float v) {
    __hip_atomic_store(p, v, __ATOMIC_RELAXED, __HIP_MEMORY_SCOPE_SYSTEM);
}
__device__ __forceinline__ void st_sysu16(unsigned short* p, unsigned short v) {
    __hip_atomic_store(p, v, __ATOMIC_RELAXED, __HIP_MEMORY_SCOPE_SYSTEM);
}

// Flush-free grid barrier. bar pre-zeroed via hipMemsetAsync each launch.
// All stores feeding this barrier are system-scope write-through, so
// s_waitcnt vmcnt(0) suffices for visibility at the coherence point.
__device__ __forceinline__ void gbar(unsigned* bar, unsigned nb) {
    asm volatile("s_waitcnt vmcnt(0) lgkmcnt(0)" ::: "memory");
    __syncthreads();
    if (threadIdx.x == 0) {
        __hip_atomic_fetch_add(bar, 1u, __ATOMIC_RELAXED, __HIP_MEMORY_SCOPE_SYSTEM);
        while (__hip_atomic_load(bar, __ATOMIC_RELAXED, __HIP_MEMORY_SCOPE_SYSTEM) < nb)
            __builtin_amdgcn_s_sleep(1);
    }
    __syncthreads();
}

// ---------------- one-time: W[k][n] fp32 -> W^T[n][k] bf16 hi/lo
__global__ __launch_bounds__(256) void split_transpose(
    const float* __restrict__ w, int K, int N,
    unsigned short* __restrict__ t_hi, unsigned short* __restrict__ t_lo)
{
    __shared__ float tile[32][33];
    int k0 = blockIdx.x * 32, n0 = blockIdx.y * 32;
    int tid = threadIdx.x;
    #pragma unroll
    for (int p = 0; p < 4; ++p) {
        int i = tid + p * 256; int r = i >> 5, c = i & 31;
        tile[r][c] = w[(size_t)(k0 + r) * N + n0 + c];
    }
    __syncthreads();
    #pragma unroll
    for (int p = 0; p < 4; ++p) {
        int i = tid + p * 256; int r = i >> 5, c = i & 31;
        float v = tile[c][r];
        unsigned short hi = f2bf(v);
        size_t o = (size_t)(n0 + r) * K + k0 + c;
        t_hi[o] = hi;
        t_lo[o] = f2bf(v - bf2f(hi));
    }
}

// ---------------- Embedding (writes x as bf16 hi/lo, [rows][384])
__global__ __launch_bounds__(256) void embed_kernel(
    const float* __restrict__ s, const float* __restrict__ a, const float* __restrict__ r,
    const float* __restrict__ Ws, const float* __restrict__ bs,
    const float* __restrict__ Wa, const float* __restrict__ ba,
    const float* __restrict__ Wr, const float* __restrict__ br,
    unsigned short* __restrict__ x_hi, unsigned short* __restrict__ x_lo)
{
    __shared__ float Ws_s[64][128];
    __shared__ float Wa_s[16][128];
    __shared__ float Wr_s[128], bs_s[128], ba_s[128], br_s[128];
    __shared__ float s_s[64][64];
    __shared__ float a_s[64][16];
    __shared__ float r_s[64];
    int tid = threadIdx.x;
    for (int i = tid; i < 64 * 128; i += 256) Ws_s[i >> 7][i & 127] = Ws[i];
    for (int i = tid; i < 16 * 128; i += 256) Wa_s[i >> 7][i & 127] = Wa[i];
    if (tid < 128) { Wr_s[tid] = Wr[tid]; bs_s[tid] = bs[tid]; ba_s[tid] = ba[tid]; br_s[tid] = br[tid]; }
    size_t row0 = (size_t)blockIdx.x * 64;
    for (int i = tid; i < 64 * 64; i += 256) s_s[i >> 6][i & 63] = s[row0 * 64 + i];
    for (int i = tid; i < 64 * 16; i += 256) a_s[i >> 4][i & 15] = a[row0 * 16 + i];
    if (tid < 64) r_s[tid] = r[row0 + tid];
    __syncthreads();
    int e = tid & 127, ty = tid >> 7;
    for (int rw = ty; rw < 64; rw += 2) {
        float accS = bs_s[e];
        #pragma unroll
        for (int k = 0; k < 64; ++k) accS += s_s[rw][k] * Ws_s[k][e];
        float accA = ba_s[e];
        #pragma unroll
        for (int k = 0; k < 16; ++k) accA += a_s[rw][k] * Wa_s[k][e];
        float accR = br_s[e] + r_s[rw] * Wr_s[e];
        float v0 = gelu_tanh(accS);
        float v1 = gelu_tanh(accA);
        float v2 = gelu_tanh(accR);
        size_t base = (row0 + rw) * X_DIM;
        unsigned short h0 = f2bf(v0), h1 = f2bf(v1), h2 = f2bf(v2);
        x_hi[base + e] = h0;        x_lo[base + e] = f2bf(v0 - bf2f(h0));
        x_hi[base + 128 + e] = h1;  x_lo[base + 128 + e] = f2bf(v1 - bf2f(h1));
        x_hi[base + 256 + e] = h2;  x_lo[base + 256 + e] = f2bf(v2 - bf2f(h2));
    }
}

// ---------------- Gates GEMM (MFMA): gx[m][n] = x[m][:] . wiT[n][:] + bias[n]
__global__ __launch_bounds__(256) void gates_mfma(
    const unsigned short* __restrict__ x_hi, const unsigned short* __restrict__ x_lo,
    const unsigned short* __restrict__ wiT_hi, const unsigned short* __restrict__ wiT_lo,
    const float* __restrict__ bias, float* __restrict__ C)
{
    const int tid = threadIdx.x;
    const int lane = tid & 63;
    const int wv = tid >> 6;
    const int wm = wv >> 1, wn = wv & 1;
    const size_t m0 = (size_t)blockIdx.y * 128 + wm * 64;
    const int n0 = blockIdx.x * 128 + wn * 64;
    const int lr = lane & 15, lk = (lane >> 4) * 8;
    f32x4 acc[4][4] = {};
    for (int k0 = 0; k0 < X_DIM; k0 += 32) {
        short8 ahi[4], alo[4], bhi[4], blo[4];
        #pragma unroll
        for (int i = 0; i < 4; ++i) {
            size_t oa = (m0 + i * 16 + lr) * X_DIM + k0 + lk;
            ahi[i] = *reinterpret_cast<const short8*>(&x_hi[oa]);
            alo[i] = *reinterpret_cast<const short8*>(&x_lo[oa]);
            size_t ob = (size_t)(n0 + i * 16 + lr) * X_DIM + k0 + lk;
            bhi[i] = *reinterpret_cast<const short8*>(&wiT_hi[ob]);
            blo[i] = *reinterpret_cast<const short8*>(&wiT_lo[ob]);
        }
        #pragma unroll
        for (int i = 0; i < 4; ++i)
            #pragma unroll
            for (int j = 0; j < 4; ++j) {
                acc[i][j] = MFMA16(ahi[i], bhi[j], acc[i][j]);
                acc[i][j] = MFMA16(ahi[i], blo[j], acc[i][j]);
                acc[i][j] = MFMA16(alo[i], bhi[j], acc[i][j]);
            }
    }
    const int rbase = (lane >> 4) * 4;
    #pragma unroll
    for (int i = 0; i < 4; ++i)
        #pragma unroll
        for (int j = 0; j < 4; ++j) {
            int colg = n0 + j * 16 + lr;
            float b = bias[colg];
            #pragma unroll
            for (int r = 0; r < 4; ++r) {
                size_t row = m0 + i * 16 + rbase + r;
                C[row * G_DIM + colg] = acc[i][j][r] + b;
            }
        }
}

// ---------------- Persistent GRU: nt steps, 2 flush-free barriers/step.
// 256 blocks x 512 threads (8 waves). Weights read with cached loads (stay
// L2-warm); all cross-block step data via system-scope (LLC) accessors.
__global__ __launch_bounds__(512) void gru_persist(
    const float* __restrict__ gx,    // nt x B x G
    int nt, int t0,
    const unsigned short* __restrict__ whT_hi, const unsigned short* __restrict__ whT_lo,
    float* __restrict__ out,         // T x B x H (full output base)
    unsigned short* __restrict__ h_hi, unsigned short* __restrict__ h_lo,
    unsigned short* __restrict__ rh_hi, unsigned short* __restrict__ rh_lo,
    float* __restrict__ zbuf,
    unsigned* __restrict__ bar)
{
    __shared__ float redbuf[1536];
    const int tid = threadIdx.x;
    const int bid = blockIdx.x;
    const int w = tid >> 6;
    const int lane = tid & 63;
    const int lr = lane & 15;
    const int lk = (lane >> 4) * 8;
    const int rbase = (lane >> 4) * 4;

    // phase A geometry: m-group (32 rows) x n-group (32 zr-cols); 4 tiles x 2 k-halves
    const int mgA = bid >> 5, ngA = bid & 31;
    const int halfA = w >> 2, widxA = w & 3;
    const int mtA = widxA >> 1, ntA = widxA & 1;
    const int arowA = mgA * 32 + mtA * 16 + lr;
    const int browA = ngA * 32 + ntA * 16 + lr;      // whT row (zr col space)
    const int kbaseA = halfA * 256 + lk;

    // phase B geometry: 512 tiles (16m x 32n) x 4 k-quarters
    const int tlB = bid * 2 + (w >> 2);
    const int qB = w & 3;
    const int m0B = (tlB >> 5) * 16;
    const int n0B = (tlB & 31) * 16;
    const int arowB = m0B + lr;
    const int browB = 1024 + n0B + lr;               // whT row (a col space)
    const int kbaseB = qB * 128 + lk;

    const unsigned nb = gridDim.x;

    for (int s = 0; s < nt; ++s) {
        const int t = t0 + s;
        const float* gxs = gx + (size_t)s * B_DIM * G_DIM;
        const float* hpf = out + (size_t)(t - 1) * B_DIM * H_DIM; // valid iff t>0
        float* out_t = out + (size_t)t * B_DIM * H_DIM;

        // ================= phase A: zr = sigmoid(gx_zr + h @ Wzr) =================
        f32x4 acc = {};
        if (t > 0) {
            const unsigned short* pah = h_hi + (size_t)arowA * H_DIM + kbaseA;
            const unsigned short* pal = h_lo + (size_t)arowA * H_DIM + kbaseA;
            const unsigned short* pbh = whT_hi + (size_t)browA * H_DIM + kbaseA;
            const unsigned short* pbl = whT_lo + (size_t)browA * H_DIM + kbaseA;
            short8 ah = ld_sys16(pah), al = ld_sys16(pal);
            short8 bh = *reinterpret_cast<const short8*>(pbh);
            short8 bl = *reinterpret_cast<const short8*>(pbl);
            for (int k0 = 0; k0 < 256; k0 += 32) {
                short8 ah2 = ah, al2 = al, bh2 = bh, bl2 = bl;
                if (k0 + 32 < 256) {
                    ah2 = ld_sys16(pah + k0 + 32);
                    al2 = ld_sys16(pal + k0 + 32);
                    bh2 = *reinterpret_cast<const short8*>(pbh + k0 + 32);
                    bl2 = *reinterpret_cast<const short8*>(pbl + k0 + 32);
                }
                acc = MFMA16(ah, bh, acc);
                acc = MFMA16(ah, bl, acc);
                acc = MFMA16(al, bh, acc);
                ah = ah2; al = al2; bh = bh2; bl = bl2;
            }
        }
        if (halfA == 1) {
            #pragma unroll
            for (int j = 0; j < 4; ++j) redbuf[widxA * 256 + lane * 4 + j] = acc[j];
        }
        __syncthreads();
        if (halfA == 0) {
            #pragma unroll
            for (int j = 0; j < 4; ++j) acc[j] += redbuf[widxA * 256 + lane * 4 + j];
            const int col = ngA * 32 + ntA * 16 + lr;   // 0..1023, wave-uniform branch
            #pragma unroll
            for (int r = 0; r < 4; ++r) {
                int row = mgA * 32 + mtA * 16 + rbase + r;
                float v = sigmoidf(gxs[(size_t)row * G_DIM + col] + acc[r]);
                if (col < H_DIM) {
                    st_sysf(zbuf + (size_t)row * H_DIM + col, v);
                } else {
                    int c = col - H_DIM;
                    float hpv = (t > 0) ? ld_sysf(hpf + (size_t)row * H_DIM + c) : 0.0f;
                    float rh = v * hpv;
                    unsigned short hi = f2bf(rh);
                    st_sysu16(rh_hi + (size_t)row * H_DIM + c, hi);
                    st_sysu16(rh_lo + (size_t)row * H_DIM + c, f2bf(rh - bf2f(hi)));
                }
            }
        }
        gbar(&bar[2 * t], nb);

        // ================= phase B: a = tanh(gx_a + rh @ Wa); h = hp + z*(a-hp) ====
        f32x4 accB = {};
        {
            const unsigned short* pah = rh_hi + (size_t)arowB * H_DIM + kbaseB;
            const unsigned short* pal = rh_lo + (size_t)arowB * H_DIM + kbaseB;
            const unsigned short* pbh = whT_hi + (size_t)browB * H_DIM + kbaseB;
            const unsigned short* pbl = whT_lo + (size_t)browB * H_DIM + kbaseB;
            short8 ah = ld_sys16(pah), al = ld_sys16(pal);
            short8 bh = *reinterpret_cast<const short8*>(pbh);
            short8 bl = *reinterpret_cast<const short8*>(pbl);
            for (int k0 = 0; k0 < 128; k0 += 32) {
                short8 ah2 = ah, al2 = al, bh2 = bh, bl2 = bl;
                if (k0 + 32 < 128) {
                    ah2 = ld_sys16(pah + k0 + 32);
                    al2 = ld_sys16(pal + k0 + 32);
                    bh2 = *reinterpret_cast<const short8*>(pbh + k0 + 32);
                    bl2 = *reinterpret_cast<const short8*>(pbl + k0 + 32);
                }
                accB = MFMA16(ah, bh, accB);
                accB = MFMA16(ah, bl, accB);
                accB = MFMA16(al, bh, accB);
                ah = ah2; al = al2; bh = bh2; bl = bl2;
            }
        }
        {
            const int slot = w >> 2;
            if (qB > 0) {
                int base = (slot * 3 + (qB - 1)) * 256;
                #pragma unroll
                for (int j = 0; j < 4; ++j) redbuf[base + lane * 4 + j] = accB[j];
            }
        }
        __syncthreads();
        if (qB == 0) {
            const int slot = w >> 2;
            #pragma unroll
            for (int p = 0; p < 3; ++p) {
                int base = (slot * 3 + p) * 256;
                #pragma unroll
                for (int j = 0; j < 4; ++j) accB[j] += redbuf[base + lane * 4 + j];
            }
            const int col = n0B + lr;
            #pragma unroll
            for (int r = 0; r < 4; ++r) {
                int row = m0B + rbase + r;
                float av = tanhf(gxs[(size_t)row * G_DIM + 1024 + col] + accB[r]);
                float hpv = (t > 0) ? ld_sysf(hpf + (size_t)row * H_DIM + col) : 0.0f;
                float z = ld_sysf(zbuf + (size_t)row * H_DIM + col);
                float hnew = hpv + z * (av - hpv);
                st_sysf(out_t + (size_t)row * H_DIM + col, hnew);
                unsigned short hi = f2bf(hnew);
                st_sysu16(h_hi + (size_t)row * H_DIM + col, hi);
                st_sysu16(h_lo + (size_t)row * H_DIM + col, f2bf(hnew - bf2f(hi)));
            }
        }
        gbar(&bar[2 * t + 1], nb);
    }
}

extern "C" void kernel_launch(void* const* d_in, const int* in_sizes, int n_in,
                              void* d_out, int out_size, void* d_ws, size_t ws_size,
                              hipStream_t stream) {
    const float* states  = (const float*)d_in[0];
    const float* actions = (const float*)d_in[1];
    const float* rewards = (const float*)d_in[2];
    const float* Ws   = (const float*)d_in[3];
    const float* bs   = (const float*)d_in[4];
    const float* Wa   = (const float*)d_in[5];
    const float* ba   = (const float*)d_in[6];
    const float* Wr   = (const float*)d_in[7];
    const float* br   = (const float*)d_in[8];
    const float* w_i  = (const float*)d_in[9];
    const float* w_h  = (const float*)d_in[10];
    const float* bgru = (const float*)d_in[11];
    float* out = (float*)d_out;

    // ---- workspace carve-up
    char* p = (char*)d_ws;
    unsigned short* whT_hi = (unsigned short*)p; p += (size_t)G_DIM * H_DIM * 2;
    unsigned short* whT_lo = (unsigned short*)p; p += (size_t)G_DIM * H_DIM * 2;
    unsigned short* wiT_hi = (unsigned short*)p; p += (size_t)G_DIM * X_DIM * 2;
    unsigned short* wiT_lo = (unsigned short*)p; p += (size_t)G_DIM * X_DIM * 2;
    float*          zbuf   = (float*)p;          p += (size_t)B_DIM * H_DIM * 4;
    unsigned short* rh_hi  = (unsigned short*)p; p += (size_t)B_DIM * H_DIM * 2;
    unsigned short* rh_lo  = (unsigned short*)p; p += (size_t)B_DIM * H_DIM * 2;
    unsigned short* h_hi   = (unsigned short*)p; p += (size_t)B_DIM * H_DIM * 2;
    unsigned short* h_lo   = (unsigned short*)p; p += (size_t)B_DIM * H_DIM * 2;
    unsigned*       bar    = (unsigned*)p;       p += 2 * T_DIM * sizeof(unsigned);
    size_t fixed = (size_t)(p - (char*)d_ws);
    size_t per_step = (size_t)B_DIM * G_DIM * 4 + (size_t)B_DIM * X_DIM * 2 * 2;
    int chunk = (int)((ws_size > fixed ? ws_size - fixed : 0) / per_step);
    if (chunk > T_DIM) chunk = T_DIM;
    if (chunk < 1) chunk = 1;
    float* gx = (float*)p;
    unsigned short* x_hi = (unsigned short*)((char*)gx + (size_t)chunk * B_DIM * G_DIM * 4);
    unsigned short* x_lo = x_hi + (size_t)chunk * B_DIM * X_DIM;

    // barrier counters must start at 0 on every call (graph replays included)
    hipMemsetAsync(bar, 0, 2 * T_DIM * sizeof(unsigned), stream);

    // ---- one-time weight split/transpose
    split_transpose<<<dim3(H_DIM / 32, G_DIM / 32), 256, 0, stream>>>(w_h, H_DIM, G_DIM, whT_hi, whT_lo);
    split_transpose<<<dim3(X_DIM / 32, G_DIM / 32), 256, 0, stream>>>(w_i, X_DIM, G_DIM, wiT_hi, wiT_lo);

    for (int t0 = 0; t0 < T_DIM; t0 += chunk) {
        int nt = (T_DIM - t0 < chunk) ? (T_DIM - t0) : chunk;
        int rows = nt * B_DIM;
        embed_kernel<<<rows / 64, 256, 0, stream>>>(
            states + (size_t)t0 * B_DIM * S_DIMS,
            actions + (size_t)t0 * B_DIM * A_DIMS,
            rewards + (size_t)t0 * B_DIM,
            Ws, bs, Wa, ba, Wr, br, x_hi, x_lo);
        dim3 ggrid(G_DIM / 128, rows / 128);
        gates_mfma<<<ggrid, 256, 0, stream>>>(x_hi, x_lo, wiT_hi, wiT_lo, bgru, gx);

        const float* gx_c = gx;
        const unsigned short *whh = whT_hi, *whl = whT_lo;
        float* out_c = out;
        unsigned short *hhi = h_hi, *hlo = h_lo, *rhi = rh_hi, *rlo = rh_lo;
        float* zb = zbuf;
        unsigned* bar_c = bar;
        int nt_c = nt, t0_c = t0;
        void* kargs[] = {(void*)&gx_c, (void*)&nt_c, (void*)&t0_c,
                         (void*)&whh, (void*)&whl, (void*)&out_c,
                         (void*)&hhi, (void*)&hlo, (void*)&rhi, (void*)&rlo,
                         (void*)&zb, (void*)&bar_c};
        hipLaunchCooperativeKernel((void*)gru_persist, dim3(256), dim3(512),
                                   kargs, 0, stream);
    }
}

// Round 11
// 14923.489 us; speedup vs baseline: 1.7035x; 1.7035x over previous
//
#include <hip/hip_runtime.h>

#define T_DIM 512
#define B_DIM 256
#define S_DIMS 64
#define A_DIMS 16
#define E_DIM 128
#define H_DIM 512
#define X_DIM 384   // 3*E
#define G_DIM 1536  // 3*H

typedef __attribute__((ext_vector_type(8))) short short8;
typedef __attribute__((ext_vector_type(4))) float f32x4;
typedef __attribute__((ext_vector_type(2))) unsigned uint2v;

#define MFMA16(a, b, c) __builtin_amdgcn_mfma_f32_16x16x32_bf16(a, b, c, 0, 0, 0)

__device__ __forceinline__ float gelu_tanh(float x) {
    const float c = 0.7978845608028654f; // sqrt(2/pi)
    float x3 = x * x * x;
    return 0.5f * x * (1.0f + tanhf(c * (x + 0.044715f * x3)));
}

__device__ __forceinline__ float sigmoidf(float x) {
    return 1.0f / (1.0f + expf(-x));
}

// round-to-nearest-even fp32 -> bf16 (as ushort)
__device__ __forceinline__ unsigned short f2bf(float x) {
    unsigned u = __float_as_uint(x);
    u += 0x7FFFu + ((u >> 16) & 1u);
    return (unsigned short)(u >> 16);
}
__device__ __forceinline__ float bf2f(unsigned short b) {
    return __uint_as_float(((unsigned)b) << 16);
}

// ---- wide L2-bypass (coherent at Infinity Cache) accessors ----
__device__ __forceinline__ f32x4 ldg_scf4_sync(const float* p) {
    f32x4 v;
    asm volatile("global_load_dwordx4 %0, %1, off sc0 sc1\n\ts_waitcnt vmcnt(0)"
                 : "=v"(v) : "v"(p));
    return v;
}
__device__ __forceinline__ void stg_scf4(float* p, f32x4 v) {
    asm volatile("global_store_dwordx4 %0, %1, off sc0 sc1" :: "v"(p), "v"(v) : "memory");
}
__device__ __forceinline__ void stg_scu2(unsigned* p, uint2v v) {
    asm volatile("global_store_dwordx2 %0, %1, off sc0 sc1" :: "v"(p), "v"(v) : "memory");
}

// Flush-free grid barrier (validated round 10). bar pre-zeroed per launch.
__device__ __forceinline__ void gbar(unsigned* bar, unsigned nb) {
    asm volatile("s_waitcnt vmcnt(0) lgkmcnt(0)" ::: "memory");
    __syncthreads();
    if (threadIdx.x == 0) {
        __hip_atomic_fetch_add(bar, 1u, __ATOMIC_RELAXED, __HIP_MEMORY_SCOPE_SYSTEM);
        while (__hip_atomic_load(bar, __ATOMIC_RELAXED, __HIP_MEMORY_SCOPE_SYSTEM) < nb)
            __builtin_amdgcn_s_sleep(1);
    }
    __syncthreads();
    __builtin_amdgcn_sched_barrier(0);
}

// ---- split-bf16 MFMA K-chain, depth-2 pipelined, counted vmcnt.
// A-operand: sc0sc1 (cross-phase data). B-operand: cached (read-only weights).
#define ISSUE_K(k) do {                                                                   \
    asm volatile("global_load_dwordx4 %0, %1, off sc0 sc1" : "=v"(fah[(k)%3]) : "v"(pah + (k)*32)); \
    asm volatile("global_load_dwordx4 %0, %1, off sc0 sc1" : "=v"(fal[(k)%3]) : "v"(pal + (k)*32)); \
    asm volatile("global_load_dwordx4 %0, %1, off"         : "=v"(fbh[(k)%3]) : "v"(pbh + (k)*32)); \
    asm volatile("global_load_dwordx4 %0, %1, off"         : "=v"(fbl[(k)%3]) : "v"(pbl + (k)*32)); \
} while (0)

template<int NK>
__device__ __forceinline__ f32x4 mfma_chain(
    const unsigned short* pah, const unsigned short* pal,
    const unsigned short* pbh, const unsigned short* pbl)
{
    short8 fah[3], fal[3], fbh[3], fbl[3];
    f32x4 acc = {};
    ISSUE_K(0);
    ISSUE_K(1);
    #pragma unroll
    for (int k = 0; k < NK; ++k) {
        if (k + 2 < NK) {
            ISSUE_K(k + 2);
            asm volatile("s_waitcnt vmcnt(8)" ::: "memory");
        } else if (k + 1 < NK) {
            asm volatile("s_waitcnt vmcnt(4)" ::: "memory");
        } else {
            asm volatile("s_waitcnt vmcnt(0)" ::: "memory");
        }
        __builtin_amdgcn_sched_barrier(0);
        acc = MFMA16(fah[k % 3], fbh[k % 3], acc);
        acc = MFMA16(fah[k % 3], fbl[k % 3], acc);
        acc = MFMA16(fal[k % 3], fbh[k % 3], acc);
    }
    return acc;
}

// ---------------- one-time: W[k][n] fp32 -> W^T[n][k] bf16 hi/lo
__global__ __launch_bounds__(256) void split_transpose(
    const float* __restrict__ w, int K, int N,
    unsigned short* __restrict__ t_hi, unsigned short* __restrict__ t_lo)
{
    __shared__ float tile[32][33];
    int k0 = blockIdx.x * 32, n0 = blockIdx.y * 32;
    int tid = threadIdx.x;
    #pragma unroll
    for (int p = 0; p < 4; ++p) {
        int i = tid + p * 256; int r = i >> 5, c = i & 31;
        tile[r][c] = w[(size_t)(k0 + r) * N + n0 + c];
    }
    __syncthreads();
    #pragma unroll
    for (int p = 0; p < 4; ++p) {
        int i = tid + p * 256; int r = i >> 5, c = i & 31;
        float v = tile[c][r];
        unsigned short hi = f2bf(v);
        size_t o = (size_t)(n0 + r) * K + k0 + c;
        t_hi[o] = hi;
        t_lo[o] = f2bf(v - bf2f(hi));
    }
}

// ---------------- Embedding (writes x as bf16 hi/lo, [rows][384])
__global__ __launch_bounds__(256) void embed_kernel(
    const float* __restrict__ s, const float* __restrict__ a, const float* __restrict__ r,
    const float* __restrict__ Ws, const float* __restrict__ bs,
    const float* __restrict__ Wa, const float* __restrict__ ba,
    const float* __restrict__ Wr, const float* __restrict__ br,
    unsigned short* __restrict__ x_hi, unsigned short* __restrict__ x_lo)
{
    __shared__ float Ws_s[64][128];
    __shared__ float Wa_s[16][128];
    __shared__ float Wr_s[128], bs_s[128], ba_s[128], br_s[128];
    __shared__ float s_s[64][64];
    __shared__ float a_s[64][16];
    __shared__ float r_s[64];
    int tid = threadIdx.x;
    for (int i = tid; i < 64 * 128; i += 256) Ws_s[i >> 7][i & 127] = Ws[i];
    for (int i = tid; i < 16 * 128; i += 256) Wa_s[i >> 7][i & 127] = Wa[i];
    if (tid < 128) { Wr_s[tid] = Wr[tid]; bs_s[tid] = bs[tid]; ba_s[tid] = ba[tid]; br_s[tid] = br[tid]; }
    size_t row0 = (size_t)blockIdx.x * 64;
    for (int i = tid; i < 64 * 64; i += 256) s_s[i >> 6][i & 63] = s[row0 * 64 + i];
    for (int i = tid; i < 64 * 16; i += 256) a_s[i >> 4][i & 15] = a[row0 * 16 + i];
    if (tid < 64) r_s[tid] = r[row0 + tid];
    __syncthreads();
    int e = tid & 127, ty = tid >> 7;
    for (int rw = ty; rw < 64; rw += 2) {
        float accS = bs_s[e];
        #pragma unroll
        for (int k = 0; k < 64; ++k) accS += s_s[rw][k] * Ws_s[k][e];
        float accA = ba_s[e];
        #pragma unroll
        for (int k = 0; k < 16; ++k) accA += a_s[rw][k] * Wa_s[k][e];
        float accR = br_s[e] + r_s[rw] * Wr_s[e];
        float v0 = gelu_tanh(accS);
        float v1 = gelu_tanh(accA);
        float v2 = gelu_tanh(accR);
        size_t base = (row0 + rw) * X_DIM;
        unsigned short h0 = f2bf(v0), h1 = f2bf(v1), h2 = f2bf(v2);
        x_hi[base + e] = h0;        x_lo[base + e] = f2bf(v0 - bf2f(h0));
        x_hi[base + 128 + e] = h1;  x_lo[base + 128 + e] = f2bf(v1 - bf2f(h1));
        x_hi[base + 256 + e] = h2;  x_lo[base + 256 + e] = f2bf(v2 - bf2f(h2));
    }
}

// ---------------- Gates GEMM (MFMA): gx[m][n] = x[m][:] . wiT[n][:] + bias[n]
__global__ __launch_bounds__(256) void gates_mfma(
    const unsigned short* __restrict__ x_hi, const unsigned short* __restrict__ x_lo,
    const unsigned short* __restrict__ wiT_hi, const unsigned short* __restrict__ wiT_lo,
    const float* __restrict__ bias, float* __restrict__ C)
{
    const int tid = threadIdx.x;
    const int lane = tid & 63;
    const int wv = tid >> 6;
    const int wm = wv >> 1, wn = wv & 1;
    const size_t m0 = (size_t)blockIdx.y * 128 + wm * 64;
    const int n0 = blockIdx.x * 128 + wn * 64;
    const int lr = lane & 15, lk = (lane >> 4) * 8;
    f32x4 acc[4][4] = {};
    for (int k0 = 0; k0 < X_DIM; k0 += 32) {
        short8 ahi[4], alo[4], bhi[4], blo[4];
        #pragma unroll
        for (int i = 0; i < 4; ++i) {
            size_t oa = (m0 + i * 16 + lr) * X_DIM + k0 + lk;
            ahi[i] = *reinterpret_cast<const short8*>(&x_hi[oa]);
            alo[i] = *reinterpret_cast<const short8*>(&x_lo[oa]);
            size_t ob = (size_t)(n0 + i * 16 + lr) * X_DIM + k0 + lk;
            bhi[i] = *reinterpret_cast<const short8*>(&wiT_hi[ob]);
            blo[i] = *reinterpret_cast<const short8*>(&wiT_lo[ob]);
        }
        #pragma unroll
        for (int i = 0; i < 4; ++i)
            #pragma unroll
            for (int j = 0; j < 4; ++j) {
                acc[i][j] = MFMA16(ahi[i], bhi[j], acc[i][j]);
                acc[i][j] = MFMA16(ahi[i], blo[j], acc[i][j]);
                acc[i][j] = MFMA16(alo[i], bhi[j], acc[i][j]);
            }
    }
    const int rbase = (lane >> 4) * 4;
    #pragma unroll
    for (int i = 0; i < 4; ++i)
        #pragma unroll
        for (int j = 0; j < 4; ++j) {
            int colg = n0 + j * 16 + lr;
            float b = bias[colg];
            #pragma unroll
            for (int r = 0; r < 4; ++r) {
                size_t row = m0 + i * 16 + rbase + r;
                C[row * G_DIM + colg] = acc[i][j][r] + b;
            }
        }
}

// ---------------- Persistent GRU: nt steps, 2 flush-free barriers/step.
// 256 blocks x 512 threads (8 waves). Weights/gx: cached loads (L2 stays warm
// forever -- no flushes). Cross-phase data (h, rh, z, out): wide sc0sc1 ops,
// coherent at the memory-side Infinity Cache.
__global__ __launch_bounds__(512) void gru_persist(
    const float* __restrict__ gx,    // nt x B x G
    int nt, int t0,
    const unsigned short* __restrict__ whT_hi, const unsigned short* __restrict__ whT_lo,
    float* __restrict__ out,         // T x B x H
    unsigned short* __restrict__ h_hi, unsigned short* __restrict__ h_lo,
    unsigned short* __restrict__ rh_hi, unsigned short* __restrict__ rh_lo,
    float* __restrict__ zbuf,
    unsigned* __restrict__ bar)
{
    __shared__ float sbuf[2560];         // [0,1536): k-reduction; [1536,2560): C tile
    const int CB = 1536;
    const int tid = threadIdx.x;
    const int bid = blockIdx.x;
    const int w = tid >> 6;
    const int lane = tid & 63;
    const int lr = lane & 15;
    const int lk = (lane >> 4) * 8;
    const int rbase = (lane >> 4) * 4;
    const unsigned nb = gridDim.x;

    // phase A geometry: (mg 8) x (ng 32) blocks; 8 waves = 2m x 2n tiles x 2 k-halves
    const int mgA = bid >> 5, ngA = bid & 31;
    const int halfA = w >> 2, widxA = w & 3;
    const int mtA = widxA >> 1, ntA = widxA & 1;
    const int arowA = mgA * 32 + mtA * 16 + lr;
    const int browA = ngA * 32 + ntA * 16 + lr;
    const int kbA = halfA * 256 + lk;

    // phase B geometry: 512 tiles (16m x 32n of 16x16); block does 2 tiles x 4 k-quarters
    const int tlB = bid * 2 + (w >> 2);
    const int qB = w & 3;
    const int slotB = w >> 2;
    const int m0B = (tlB >> 5) * 16;
    const int n0B = (tlB & 31) * 16;
    const int arowB = m0B + lr;
    const int browB = 1024 + n0B + lr;
    const int kbB = qB * 128 + lk;

    for (int s = 0; s < nt; ++s) {
        const int t = t0 + s;
        const float* gxs = gx + (size_t)s * B_DIM * G_DIM;
        const float* hpf = out + (size_t)(t - 1) * B_DIM * H_DIM; // valid iff t>0
        float* out_t = out + (size_t)t * B_DIM * H_DIM;

        // ================= phase A: zr = sigmoid(gx_zr + h @ Wzr) =================
        f32x4 acc = {};
        if (t > 0) {
            acc = mfma_chain<8>(h_hi + (size_t)arowA * H_DIM + kbA,
                                h_lo + (size_t)arowA * H_DIM + kbA,
                                whT_hi + (size_t)browA * H_DIM + kbA,
                                whT_lo + (size_t)browA * H_DIM + kbA);
        }
        if (halfA == 1) {
            #pragma unroll
            for (int j = 0; j < 4; ++j) sbuf[widxA * 256 + lane * 4 + j] = acc[j];
        }
        __syncthreads();
        if (halfA == 0) {
            #pragma unroll
            for (int j = 0; j < 4; ++j) acc[j] += sbuf[widxA * 256 + lane * 4 + j];
            #pragma unroll
            for (int r = 0; r < 4; ++r)
                sbuf[CB + (mtA * 16 + rbase + r) * 32 + ntA * 16 + lr] = acc[r];
        }
        __syncthreads();
        if (tid < 256) {
            int row_l = tid >> 3;
            int c4 = (tid & 7) * 4;
            int row = mgA * 32 + row_l;
            int colA = ngA * 32 + c4;
            f32x4 g = *reinterpret_cast<const f32x4*>(&gxs[(size_t)row * G_DIM + colA]);
            f32x4 v;
            #pragma unroll
            for (int j = 0; j < 4; ++j)
                v[j] = sigmoidf(g[j] + sbuf[CB + row_l * 32 + c4 + j]);
            if (ngA < 16) {
                stg_scf4(zbuf + (size_t)row * H_DIM + colA, v);
            } else {
                int c = colA - H_DIM;
                f32x4 hp = {};
                if (t > 0) hp = ldg_scf4_sync(hpf + (size_t)row * H_DIM + c);
                f32x4 rh;
                #pragma unroll
                for (int j = 0; j < 4; ++j) rh[j] = v[j] * hp[j];
                unsigned short e0 = f2bf(rh[0]), e1 = f2bf(rh[1]), e2 = f2bf(rh[2]), e3 = f2bf(rh[3]);
                uint2v uh = { (unsigned)e0 | ((unsigned)e1 << 16), (unsigned)e2 | ((unsigned)e3 << 16) };
                stg_scu2((unsigned*)(rh_hi + (size_t)row * H_DIM + c), uh);
                unsigned short l0 = f2bf(rh[0] - bf2f(e0)), l1 = f2bf(rh[1] - bf2f(e1));
                unsigned short l2 = f2bf(rh[2] - bf2f(e2)), l3 = f2bf(rh[3] - bf2f(e3));
                uint2v ul = { (unsigned)l0 | ((unsigned)l1 << 16), (unsigned)l2 | ((unsigned)l3 << 16) };
                stg_scu2((unsigned*)(rh_lo + (size_t)row * H_DIM + c), ul);
            }
        }
        gbar(&bar[2 * t], nb);

        // ================= phase B: a = tanh(gx_a + rh @ Wa); h = hp + z*(a-hp) ====
        f32x4 accB = mfma_chain<4>(rh_hi + (size_t)arowB * H_DIM + kbB,
                                   rh_lo + (size_t)arowB * H_DIM + kbB,
                                   whT_hi + (size_t)browB * H_DIM + kbB,
                                   whT_lo + (size_t)browB * H_DIM + kbB);
        if (qB > 0) {
            int base = (slotB * 3 + (qB - 1)) * 256;
            #pragma unroll
            for (int j = 0; j < 4; ++j) sbuf[base + lane * 4 + j] = accB[j];
        }
        __syncthreads();
        if (qB == 0) {
            #pragma unroll
            for (int p = 0; p < 3; ++p) {
                int base = (slotB * 3 + p) * 256;
                #pragma unroll
                for (int j = 0; j < 4; ++j) accB[j] += sbuf[base + lane * 4 + j];
            }
            #pragma unroll
            for (int r = 0; r < 4; ++r)
                sbuf[CB + slotB * 256 + (rbase + r) * 16 + lr] = accB[r];
        }
        __syncthreads();
        if (tid < 128) {
            int tl = tid >> 6;
            int row_l = (tid >> 2) & 15;
            int c4 = (tid & 3) * 4;
            int tlg = bid * 2 + tl;
            int row = (tlg >> 5) * 16 + row_l;
            int col = (tlg & 31) * 16 + c4;
            f32x4 g = *reinterpret_cast<const f32x4*>(&gxs[(size_t)row * G_DIM + 1024 + col]);
            f32x4 hp = {};
            if (t > 0) hp = ldg_scf4_sync(hpf + (size_t)row * H_DIM + col);
            f32x4 z = ldg_scf4_sync(zbuf + (size_t)row * H_DIM + col);
            f32x4 hnew;
            #pragma unroll
            for (int j = 0; j < 4; ++j) {
                float av = tanhf(g[j] + sbuf[CB + tl * 256 + row_l * 16 + c4 + j]);
                hnew[j] = hp[j] + z[j] * (av - hp[j]);
            }
            stg_scf4(out_t + (size_t)row * H_DIM + col, hnew);
            unsigned short e0 = f2bf(hnew[0]), e1 = f2bf(hnew[1]), e2 = f2bf(hnew[2]), e3 = f2bf(hnew[3]);
            uint2v uh = { (unsigned)e0 | ((unsigned)e1 << 16), (unsigned)e2 | ((unsigned)e3 << 16) };
            stg_scu2((unsigned*)(h_hi + (size_t)row * H_DIM + col), uh);
            unsigned short l0 = f2bf(hnew[0] - bf2f(e0)), l1 = f2bf(hnew[1] - bf2f(e1));
            unsigned short l2 = f2bf(hnew[2] - bf2f(e2)), l3 = f2bf(hnew[3] - bf2f(e3));
            uint2v ul = { (unsigned)l0 | ((unsigned)l1 << 16), (unsigned)l2 | ((unsigned)l3 << 16) };
            stg_scu2((unsigned*)(h_lo + (size_t)row * H_DIM + col), ul);
        }
        gbar(&bar[2 * t + 1], nb);
    }
}

extern "C" void kernel_launch(void* const* d_in, const int* in_sizes, int n_in,
                              void* d_out, int out_size, void* d_ws, size_t ws_size,
                              hipStream_t stream) {
    const float* states  = (const float*)d_in[0];
    const float* actions = (const float*)d_in[1];
    const float* rewards = (const float*)d_in[2];
    const float* Ws   = (const float*)d_in[3];
    const float* bs   = (const float*)d_in[4];
    const float* Wa   = (const float*)d_in[5];
    const float* ba   = (const float*)d_in[6];
    const float* Wr   = (const float*)d_in[7];
    const float* br   = (const float*)d_in[8];
    const float* w_i  = (const float*)d_in[9];
    const float* w_h  = (const float*)d_in[10];
    const float* bgru = (const float*)d_in[11];
    float* out = (float*)d_out;

    // ---- workspace carve-up
    char* p = (char*)d_ws;
    unsigned short* whT_hi = (unsigned short*)p; p += (size_t)G_DIM * H_DIM * 2;
    unsigned short* whT_lo = (unsigned short*)p; p += (size_t)G_DIM * H_DIM * 2;
    unsigned short* wiT_hi = (unsigned short*)p; p += (size_t)G_DIM * X_DIM * 2;
    unsigned short* wiT_lo = (unsigned short*)p; p += (size_t)G_DIM * X_DIM * 2;
    float*          zbuf   = (float*)p;          p += (size_t)B_DIM * H_DIM * 4;
    unsigned short* rh_hi  = (unsigned short*)p; p += (size_t)B_DIM * H_DIM * 2;
    unsigned short* rh_lo  = (unsigned short*)p; p += (size_t)B_DIM * H_DIM * 2;
    unsigned short* h_hi   = (unsigned short*)p; p += (size_t)B_DIM * H_DIM * 2;
    unsigned short* h_lo   = (unsigned short*)p; p += (size_t)B_DIM * H_DIM * 2;
    unsigned*       bar    = (unsigned*)p;       p += 2 * T_DIM * sizeof(unsigned);
    size_t fixed = (size_t)(p - (char*)d_ws);
    size_t per_step = (size_t)B_DIM * G_DIM * 4 + (size_t)B_DIM * X_DIM * 2 * 2;
    int chunk = (int)((ws_size > fixed ? ws_size - fixed : 0) / per_step);
    if (chunk > T_DIM) chunk = T_DIM;
    if (chunk < 1) chunk = 1;
    float* gx = (float*)p;
    unsigned short* x_hi = (unsigned short*)((char*)gx + (size_t)chunk * B_DIM * G_DIM * 4);
    unsigned short* x_lo = x_hi + (size_t)chunk * B_DIM * X_DIM;

    // barrier counters must start at 0 on every call (graph replays included)
    hipMemsetAsync(bar, 0, 2 * T_DIM * sizeof(unsigned), stream);

    // ---- one-time weight split/transpose
    split_transpose<<<dim3(H_DIM / 32, G_DIM / 32), 256, 0, stream>>>(w_h, H_DIM, G_DIM, whT_hi, whT_lo);
    split_transpose<<<dim3(X_DIM / 32, G_DIM / 32), 256, 0, stream>>>(w_i, X_DIM, G_DIM, wiT_hi, wiT_lo);

    for (int t0 = 0; t0 < T_DIM; t0 += chunk) {
        int nt = (T_DIM - t0 < chunk) ? (T_DIM - t0) : chunk;
        int rows = nt * B_DIM;
        embed_kernel<<<rows / 64, 256, 0, stream>>>(
            states + (size_t)t0 * B_DIM * S_DIMS,
            actions + (size_t)t0 * B_DIM * A_DIMS,
            rewards + (size_t)t0 * B_DIM,
            Ws, bs, Wa, ba, Wr, br, x_hi, x_lo);
        dim3 ggrid(G_DIM / 128, rows / 128);
        gates_mfma<<<ggrid, 256, 0, stream>>>(x_hi, x_lo, wiT_hi, wiT_lo, bgru, gx);

        const float* gx_c = gx;
        const unsigned short *whh = whT_hi, *whl = whT_lo;
        float* out_c = out;
        unsigned short *hhi = h_hi, *hlo = h_lo, *rhi = rh_hi, *rlo = rh_lo;
        float* zb = zbuf;
        unsigned* bar_c = bar;
        int nt_c = nt, t0_c = t0;
        void* kargs[] = {(void*)&gx_c, (void*)&nt_c, (void*)&t0_c,
                         (void*)&whh, (void*)&whl, (void*)&out_c,
                         (void*)&hhi, (void*)&hlo, (void*)&rhi, (void*)&rlo,
                         (void*)&zb, (void*)&bar_c};
        hipLaunchCooperativeKernel((void*)gru_persist, dim3(256), dim3(512),
                                   kargs, 0, stream);
    }
}

// Round 12
// 11352.843 us; speedup vs baseline: 2.2393x; 1.3145x over previous
//
#include <hip/hip_runtime.h>

#define T_DIM 512
#define B_DIM 256
#define S_DIMS 64
#define A_DIMS 16
#define E_DIM 128
#define H_DIM 512
#define X_DIM 384   // 3*E
#define G_DIM 1536  // 3*H
#define BAR_STRIDE 160   // uints per barrier instance (8 groups*16 + root at 128)

typedef __attribute__((ext_vector_type(8))) short short8;
typedef __attribute__((ext_vector_type(4))) float f32x4;
typedef __attribute__((ext_vector_type(2))) unsigned uint2v;

#define MFMA16(a, b, c) __builtin_amdgcn_mfma_f32_16x16x32_bf16(a, b, c, 0, 0, 0)

__device__ __forceinline__ float gelu_tanh(float x) {
    const float c = 0.7978845608028654f; // sqrt(2/pi)
    float x3 = x * x * x;
    return 0.5f * x * (1.0f + tanhf(c * (x + 0.044715f * x3)));
}

__device__ __forceinline__ float sigmoidf(float x) {
    return 1.0f / (1.0f + expf(-x));
}

// round-to-nearest-even fp32 -> bf16 (as ushort)
__device__ __forceinline__ unsigned short f2bf(float x) {
    unsigned u = __float_as_uint(x);
    u += 0x7FFFu + ((u >> 16) & 1u);
    return (unsigned short)(u >> 16);
}
__device__ __forceinline__ float bf2f(unsigned short b) {
    return __uint_as_float(((unsigned)b) << 16);
}

// ---- wide L2-bypass (coherent at Infinity Cache) accessors ----
__device__ __forceinline__ void stg_scf4(float* p, f32x4 v) {
    asm volatile("global_store_dwordx4 %0, %1, off sc0 sc1" :: "v"(p), "v"(v) : "memory");
}
__device__ __forceinline__ void stg_scu2(unsigned* p, uint2v v) {
    asm volatile("global_store_dwordx2 %0, %1, off sc0 sc1" :: "v"(p), "v"(v) : "memory");
}

// Two-level flush-free grid barrier. 8 group counters (64B apart) + root.
// b points at this instance's 160-uint region (pre-zeroed each launch).
__device__ __forceinline__ void gbar(unsigned* b) {
    asm volatile("s_waitcnt vmcnt(0) lgkmcnt(0)" ::: "memory");
    __syncthreads();
    if (threadIdx.x == 0) {
        unsigned* gc = b + (blockIdx.x & 7) * 16;
        unsigned* root = b + 128;
        if (__hip_atomic_fetch_add(gc, 1u, __ATOMIC_RELAXED, __HIP_MEMORY_SCOPE_SYSTEM) == 31u)
            __hip_atomic_fetch_add(root, 1u, __ATOMIC_RELAXED, __HIP_MEMORY_SCOPE_SYSTEM);
        while (__hip_atomic_load(root, __ATOMIC_RELAXED, __HIP_MEMORY_SCOPE_SYSTEM) < 8u)
            __builtin_amdgcn_s_sleep(1);
    }
    __syncthreads();
    __builtin_amdgcn_sched_barrier(0);
}

// ---- fully-unrolled split-bf16 MFMA chain pieces ----
// A-operand (h/rh): sc0sc1 bypass loads. B-operand (weights): cached.
#define ISSUE4(k) do {                                                                              \
    asm volatile("global_load_dwordx4 %0, %1, off sc0 sc1" : "=v"(fah[k]) : "v"(pah + (k) * 32));   \
    asm volatile("global_load_dwordx4 %0, %1, off sc0 sc1" : "=v"(fal[k]) : "v"(pal + (k) * 32));   \
    asm volatile("global_load_dwordx4 %0, %1, off"         : "=v"(fbh[k]) : "v"(pbh + (k) * 32));   \
    asm volatile("global_load_dwordx4 %0, %1, off"         : "=v"(fbl[k]) : "v"(pbl + (k) * 32));   \
} while (0)

#define CHAIN_STEP(k, n) do {                                  \
    asm volatile("s_waitcnt vmcnt(" #n ")" ::: "memory");      \
    __builtin_amdgcn_sched_barrier(0);                         \
    a0 = MFMA16(fah[k], fbh[k], a0);                           \
    a1 = MFMA16(fah[k], fbl[k], a1);                           \
    a2 = MFMA16(fal[k], fbh[k], a2);                           \
} while (0)

// ---------------- one-time: W[k][n] fp32 -> W^T[n][k] bf16 hi/lo
__global__ __launch_bounds__(256) void split_transpose(
    const float* __restrict__ w, int K, int N,
    unsigned short* __restrict__ t_hi, unsigned short* __restrict__ t_lo)
{
    __shared__ float tile[32][33];
    int k0 = blockIdx.x * 32, n0 = blockIdx.y * 32;
    int tid = threadIdx.x;
    #pragma unroll
    for (int p = 0; p < 4; ++p) {
        int i = tid + p * 256; int r = i >> 5, c = i & 31;
        tile[r][c] = w[(size_t)(k0 + r) * N + n0 + c];
    }
    __syncthreads();
    #pragma unroll
    for (int p = 0; p < 4; ++p) {
        int i = tid + p * 256; int r = i >> 5, c = i & 31;
        float v = tile[c][r];
        unsigned short hi = f2bf(v);
        size_t o = (size_t)(n0 + r) * K + k0 + c;
        t_hi[o] = hi;
        t_lo[o] = f2bf(v - bf2f(hi));
    }
}

// ---------------- Embedding (writes x as bf16 hi/lo, [rows][384])
__global__ __launch_bounds__(256) void embed_kernel(
    const float* __restrict__ s, const float* __restrict__ a, const float* __restrict__ r,
    const float* __restrict__ Ws, const float* __restrict__ bs,
    const float* __restrict__ Wa, const float* __restrict__ ba,
    const float* __restrict__ Wr, const float* __restrict__ br,
    unsigned short* __restrict__ x_hi, unsigned short* __restrict__ x_lo)
{
    __shared__ float Ws_s[64][128];
    __shared__ float Wa_s[16][128];
    __shared__ float Wr_s[128], bs_s[128], ba_s[128], br_s[128];
    __shared__ float s_s[64][64];
    __shared__ float a_s[64][16];
    __shared__ float r_s[64];
    int tid = threadIdx.x;
    for (int i = tid; i < 64 * 128; i += 256) Ws_s[i >> 7][i & 127] = Ws[i];
    for (int i = tid; i < 16 * 128; i += 256) Wa_s[i >> 7][i & 127] = Wa[i];
    if (tid < 128) { Wr_s[tid] = Wr[tid]; bs_s[tid] = bs[tid]; ba_s[tid] = ba[tid]; br_s[tid] = br[tid]; }
    size_t row0 = (size_t)blockIdx.x * 64;
    for (int i = tid; i < 64 * 64; i += 256) s_s[i >> 6][i & 63] = s[row0 * 64 + i];
    for (int i = tid; i < 64 * 16; i += 256) a_s[i >> 4][i & 15] = a[row0 * 16 + i];
    if (tid < 64) r_s[tid] = r[row0 + tid];
    __syncthreads();
    int e = tid & 127, ty = tid >> 7;
    for (int rw = ty; rw < 64; rw += 2) {
        float accS = bs_s[e];
        #pragma unroll
        for (int k = 0; k < 64; ++k) accS += s_s[rw][k] * Ws_s[k][e];
        float accA = ba_s[e];
        #pragma unroll
        for (int k = 0; k < 16; ++k) accA += a_s[rw][k] * Wa_s[k][e];
        float accR = br_s[e] + r_s[rw] * Wr_s[e];
        float v0 = gelu_tanh(accS);
        float v1 = gelu_tanh(accA);
        float v2 = gelu_tanh(accR);
        size_t base = (row0 + rw) * X_DIM;
        unsigned short h0 = f2bf(v0), h1 = f2bf(v1), h2 = f2bf(v2);
        x_hi[base + e] = h0;        x_lo[base + e] = f2bf(v0 - bf2f(h0));
        x_hi[base + 128 + e] = h1;  x_lo[base + 128 + e] = f2bf(v1 - bf2f(h1));
        x_hi[base + 256 + e] = h2;  x_lo[base + 256 + e] = f2bf(v2 - bf2f(h2));
    }
}

// ---------------- Gates GEMM (MFMA): gx[m][n] = x[m][:] . wiT[n][:] + bias[n]
__global__ __launch_bounds__(256) void gates_mfma(
    const unsigned short* __restrict__ x_hi, const unsigned short* __restrict__ x_lo,
    const unsigned short* __restrict__ wiT_hi, const unsigned short* __restrict__ wiT_lo,
    const float* __restrict__ bias, float* __restrict__ C)
{
    const int tid = threadIdx.x;
    const int lane = tid & 63;
    const int wv = tid >> 6;
    const int wm = wv >> 1, wn = wv & 1;
    const size_t m0 = (size_t)blockIdx.y * 128 + wm * 64;
    const int n0 = blockIdx.x * 128 + wn * 64;
    const int lr = lane & 15, lk = (lane >> 4) * 8;
    f32x4 acc[4][4] = {};
    for (int k0 = 0; k0 < X_DIM; k0 += 32) {
        short8 ahi[4], alo[4], bhi[4], blo[4];
        #pragma unroll
        for (int i = 0; i < 4; ++i) {
            size_t oa = (m0 + i * 16 + lr) * X_DIM + k0 + lk;
            ahi[i] = *reinterpret_cast<const short8*>(&x_hi[oa]);
            alo[i] = *reinterpret_cast<const short8*>(&x_lo[oa]);
            size_t ob = (size_t)(n0 + i * 16 + lr) * X_DIM + k0 + lk;
            bhi[i] = *reinterpret_cast<const short8*>(&wiT_hi[ob]);
            blo[i] = *reinterpret_cast<const short8*>(&wiT_lo[ob]);
        }
        #pragma unroll
        for (int i = 0; i < 4; ++i)
            #pragma unroll
            for (int j = 0; j < 4; ++j) {
                acc[i][j] = MFMA16(ahi[i], bhi[j], acc[i][j]);
                acc[i][j] = MFMA16(ahi[i], blo[j], acc[i][j]);
                acc[i][j] = MFMA16(alo[i], bhi[j], acc[i][j]);
            }
    }
    const int rbase = (lane >> 4) * 4;
    #pragma unroll
    for (int i = 0; i < 4; ++i)
        #pragma unroll
        for (int j = 0; j < 4; ++j) {
            int colg = n0 + j * 16 + lr;
            float b = bias[colg];
            #pragma unroll
            for (int r = 0; r < 4; ++r) {
                size_t row = m0 + i * 16 + rbase + r;
                C[row * G_DIM + colg] = acc[i][j][r] + b;
            }
        }
}

// ---------------- Persistent GRU: nt steps, 2 tree barriers/step.
__global__ __launch_bounds__(512) void gru_persist(
    const float* __restrict__ gx,    // nt x B x G
    int nt, int t0,
    const unsigned short* __restrict__ whT_hi, const unsigned short* __restrict__ whT_lo,
    float* __restrict__ out,         // T x B x H
    unsigned short* __restrict__ h_hi, unsigned short* __restrict__ h_lo,
    unsigned short* __restrict__ rh_hi, unsigned short* __restrict__ rh_lo,
    float* __restrict__ zbuf,
    unsigned* __restrict__ bar)
{
    __shared__ float sbuf[2560];         // [0,1536): k-reduction; [1536,2560): C tile
    const int CB = 1536;
    const int tid = threadIdx.x;
    const int bid = blockIdx.x;
    const int w = tid >> 6;
    const int lane = tid & 63;
    const int lr = lane & 15;
    const int lk = (lane >> 4) * 8;
    const int rbase = (lane >> 4) * 4;

    // phase A geometry: (mg 8) x (ng 32) blocks; 8 waves = 2m x 2n tiles x 2 k-halves
    const int mgA = bid >> 5, ngA = bid & 31;
    const int halfA = w >> 2, widxA = w & 3;
    const int mtA = widxA >> 1, ntA = widxA & 1;
    const int arowA = mgA * 32 + mtA * 16 + lr;
    const int browA = ngA * 32 + ntA * 16 + lr;
    const int kbA = halfA * 256 + lk;
    // phase A epilogue coords
    const int erowlA = tid >> 3, ec4A = (tid & 7) * 4;
    const int erowA = mgA * 32 + erowlA;
    const int ecolA = ngA * 32 + ec4A;

    // phase B geometry: 512 tiles (16m x 32n of 16x16); block does 2 tiles x 4 k-quarters
    const int tlB = bid * 2 + (w >> 2);
    const int qB = w & 3;
    const int slotB = w >> 2;
    const int m0B = (tlB >> 5) * 16;
    const int n0B = (tlB & 31) * 16;
    const int arowB = m0B + lr;
    const int browB = 1024 + n0B + lr;
    const int kbB = qB * 128 + lk;
    // phase B epilogue coords
    const int etlB = tid >> 6;
    const int erowlB = (tid >> 2) & 15;
    const int ec4B = (tid & 3) * 4;
    const int etlgB = bid * 2 + etlB;
    const int erowB = (etlgB >> 5) * 16 + erowlB;
    const int ecolB = (etlgB & 31) * 16 + ec4B;

    for (int s = 0; s < nt; ++s) {
        const int t = t0 + s;
        const float* gxs = gx + (size_t)s * B_DIM * G_DIM;
        const float* hpf = out + (size_t)(t - 1) * B_DIM * H_DIM; // valid iff t>0
        float* out_t = out + (size_t)t * B_DIM * H_DIM;

        // ================= phase A: zr = sigmoid(gx_zr + h @ Wzr) =================
        f32x4 acc = {};
        if (t > 0) {
            const unsigned short* pah = h_hi + (size_t)arowA * H_DIM + kbA;
            const unsigned short* pal = h_lo + (size_t)arowA * H_DIM + kbA;
            const unsigned short* pbh = whT_hi + (size_t)browA * H_DIM + kbA;
            const unsigned short* pbl = whT_lo + (size_t)browA * H_DIM + kbA;
            short8 fah[8], fal[8], fbh[8], fbl[8];
            f32x4 a0 = {}, a1 = {}, a2 = {};
            ISSUE4(0); ISSUE4(1); ISSUE4(2); ISSUE4(3);
            ISSUE4(4); ISSUE4(5); ISSUE4(6); ISSUE4(7);
            CHAIN_STEP(0, 28); CHAIN_STEP(1, 24); CHAIN_STEP(2, 20); CHAIN_STEP(3, 16);
            CHAIN_STEP(4, 12); CHAIN_STEP(5, 8);  CHAIN_STEP(6, 4);  CHAIN_STEP(7, 0);
            acc = a0 + a1;
            acc = acc + a2;
        }
        if (halfA == 1) {
            #pragma unroll
            for (int j = 0; j < 4; ++j) sbuf[widxA * 256 + lane * 4 + j] = acc[j];
        }
        // epilogue prefetch: hp (cached -- out[t-1] addresses are fresh each step)
        f32x4 hp_pre = {};
        if (tid < 256 && ngA >= 16 && t > 0)
            asm volatile("global_load_dwordx4 %0, %1, off"
                         : "=v"(hp_pre) : "v"(hpf + (size_t)erowA * H_DIM + (ecolA - H_DIM)));
        __syncthreads();
        if (halfA == 0) {
            #pragma unroll
            for (int j = 0; j < 4; ++j) acc[j] += sbuf[widxA * 256 + lane * 4 + j];
            #pragma unroll
            for (int r = 0; r < 4; ++r)
                sbuf[CB + (mtA * 16 + rbase + r) * 32 + ntA * 16 + lr] = acc[r];
        }
        __syncthreads();
        if (tid < 256) {
            f32x4 g = *reinterpret_cast<const f32x4*>(&gxs[(size_t)erowA * G_DIM + ecolA]);
            f32x4 v;
            #pragma unroll
            for (int j = 0; j < 4; ++j)
                v[j] = sigmoidf(g[j] + sbuf[CB + erowlA * 32 + ec4A + j]);
            if (ngA < 16) {
                stg_scf4(zbuf + (size_t)erowA * H_DIM + ecolA, v);
            } else {
                asm volatile("s_waitcnt vmcnt(0)" ::: "memory");
                __builtin_amdgcn_sched_barrier(0);
                int c = ecolA - H_DIM;
                f32x4 rh;
                #pragma unroll
                for (int j = 0; j < 4; ++j) rh[j] = v[j] * hp_pre[j];
                unsigned short e0 = f2bf(rh[0]), e1 = f2bf(rh[1]), e2 = f2bf(rh[2]), e3 = f2bf(rh[3]);
                uint2v uh = { (unsigned)e0 | ((unsigned)e1 << 16), (unsigned)e2 | ((unsigned)e3 << 16) };
                stg_scu2((unsigned*)(rh_hi + (size_t)erowA * H_DIM + c), uh);
                unsigned short l0 = f2bf(rh[0] - bf2f(e0)), l1 = f2bf(rh[1] - bf2f(e1));
                unsigned short l2 = f2bf(rh[2] - bf2f(e2)), l3 = f2bf(rh[3] - bf2f(e3));
                uint2v ul = { (unsigned)l0 | ((unsigned)l1 << 16), (unsigned)l2 | ((unsigned)l3 << 16) };
                stg_scu2((unsigned*)(rh_lo + (size_t)erowA * H_DIM + c), ul);
            }
        }
        gbar(bar + (size_t)(2 * t) * BAR_STRIDE);

        // ================= phase B: a = tanh(gx_a + rh @ Wa); h = hp + z*(a-hp) ====
        f32x4 accB;
        {
            const unsigned short* pah = rh_hi + (size_t)arowB * H_DIM + kbB;
            const unsigned short* pal = rh_lo + (size_t)arowB * H_DIM + kbB;
            const unsigned short* pbh = whT_hi + (size_t)browB * H_DIM + kbB;
            const unsigned short* pbl = whT_lo + (size_t)browB * H_DIM + kbB;
            short8 fah[4], fal[4], fbh[4], fbl[4];
            f32x4 a0 = {}, a1 = {}, a2 = {};
            ISSUE4(0); ISSUE4(1); ISSUE4(2); ISSUE4(3);
            CHAIN_STEP(0, 12); CHAIN_STEP(1, 8); CHAIN_STEP(2, 4); CHAIN_STEP(3, 0);
            accB = a0 + a1;
            accB = accB + a2;
        }
        // epilogue prefetch: hp (cached, fresh addresses) + z (sc, reused buffer)
        f32x4 hpB = {}, zvB = {};
        if (tid < 128) {
            if (t > 0)
                asm volatile("global_load_dwordx4 %0, %1, off"
                             : "=v"(hpB) : "v"(hpf + (size_t)erowB * H_DIM + ecolB));
            asm volatile("global_load_dwordx4 %0, %1, off sc0 sc1"
                         : "=v"(zvB) : "v"(zbuf + (size_t)erowB * H_DIM + ecolB));
        }
        if (qB > 0) {
            int base = (slotB * 3 + (qB - 1)) * 256;
            #pragma unroll
            for (int j = 0; j < 4; ++j) sbuf[base + lane * 4 + j] = accB[j];
        }
        __syncthreads();
        if (qB == 0) {
            #pragma unroll
            for (int p = 0; p < 3; ++p) {
                int base = (slotB * 3 + p) * 256;
                #pragma unroll
                for (int j = 0; j < 4; ++j) accB[j] += sbuf[base + lane * 4 + j];
            }
            #pragma unroll
            for (int r = 0; r < 4; ++r)
                sbuf[CB + slotB * 256 + (rbase + r) * 16 + lr] = accB[r];
        }
        __syncthreads();
        if (tid < 128) {
            f32x4 g = *reinterpret_cast<const f32x4*>(&gxs[(size_t)erowB * G_DIM + 1024 + ecolB]);
            asm volatile("s_waitcnt vmcnt(0)" ::: "memory");
            __builtin_amdgcn_sched_barrier(0);
            f32x4 hnew;
            #pragma unroll
            for (int j = 0; j < 4; ++j) {
                float av = tanhf(g[j] + sbuf[CB + etlB * 256 + erowlB * 16 + ec4B + j]);
                hnew[j] = hpB[j] + zvB[j] * (av - hpB[j]);
            }
            stg_scf4(out_t + (size_t)erowB * H_DIM + ecolB, hnew);
            unsigned short e0 = f2bf(hnew[0]), e1 = f2bf(hnew[1]), e2 = f2bf(hnew[2]), e3 = f2bf(hnew[3]);
            uint2v uh = { (unsigned)e0 | ((unsigned)e1 << 16), (unsigned)e2 | ((unsigned)e3 << 16) };
            stg_scu2((unsigned*)(h_hi + (size_t)erowB * H_DIM + ecolB), uh);
            unsigned short l0 = f2bf(hnew[0] - bf2f(e0)), l1 = f2bf(hnew[1] - bf2f(e1));
            unsigned short l2 = f2bf(hnew[2] - bf2f(e2)), l3 = f2bf(hnew[3] - bf2f(e3));
            uint2v ul = { (unsigned)l0 | ((unsigned)l1 << 16), (unsigned)l2 | ((unsigned)l3 << 16) };
            stg_scu2((unsigned*)(h_lo + (size_t)erowB * H_DIM + ecolB), ul);
        }
        gbar(bar + (size_t)(2 * t + 1) * BAR_STRIDE);
    }
}

extern "C" void kernel_launch(void* const* d_in, const int* in_sizes, int n_in,
                              void* d_out, int out_size, void* d_ws, size_t ws_size,
                              hipStream_t stream) {
    const float* states  = (const float*)d_in[0];
    const float* actions = (const float*)d_in[1];
    const float* rewards = (const float*)d_in[2];
    const float* Ws   = (const float*)d_in[3];
    const float* bs   = (const float*)d_in[4];
    const float* Wa   = (const float*)d_in[5];
    const float* ba   = (const float*)d_in[6];
    const float* Wr   = (const float*)d_in[7];
    const float* br   = (const float*)d_in[8];
    const float* w_i  = (const float*)d_in[9];
    const float* w_h  = (const float*)d_in[10];
    const float* bgru = (const float*)d_in[11];
    float* out = (float*)d_out;

    // ---- workspace carve-up
    char* p = (char*)d_ws;
    unsigned short* whT_hi = (unsigned short*)p; p += (size_t)G_DIM * H_DIM * 2;
    unsigned short* whT_lo = (unsigned short*)p; p += (size_t)G_DIM * H_DIM * 2;
    unsigned short* wiT_hi = (unsigned short*)p; p += (size_t)G_DIM * X_DIM * 2;
    unsigned short* wiT_lo = (unsigned short*)p; p += (size_t)G_DIM * X_DIM * 2;
    float*          zbuf   = (float*)p;          p += (size_t)B_DIM * H_DIM * 4;
    unsigned short* rh_hi  = (unsigned short*)p; p += (size_t)B_DIM * H_DIM * 2;
    unsigned short* rh_lo  = (unsigned short*)p; p += (size_t)B_DIM * H_DIM * 2;
    unsigned short* h_hi   = (unsigned short*)p; p += (size_t)B_DIM * H_DIM * 2;
    unsigned short* h_lo   = (unsigned short*)p; p += (size_t)B_DIM * H_DIM * 2;
    unsigned*       bar    = (unsigned*)p;       p += (size_t)2 * T_DIM * BAR_STRIDE * sizeof(unsigned);
    size_t fixed = (size_t)(p - (char*)d_ws);
    size_t per_step = (size_t)B_DIM * G_DIM * 4 + (size_t)B_DIM * X_DIM * 2 * 2;
    int chunk = (int)((ws_size > fixed ? ws_size - fixed : 0) / per_step);
    if (chunk > T_DIM) chunk = T_DIM;
    if (chunk < 1) chunk = 1;
    float* gx = (float*)p;
    unsigned short* x_hi = (unsigned short*)((char*)gx + (size_t)chunk * B_DIM * G_DIM * 4);
    unsigned short* x_lo = x_hi + (size_t)chunk * B_DIM * X_DIM;

    // barrier counters must start at 0 on every call (graph replays included)
    hipMemsetAsync(bar, 0, (size_t)2 * T_DIM * BAR_STRIDE * sizeof(unsigned), stream);

    // ---- one-time weight split/transpose
    split_transpose<<<dim3(H_DIM / 32, G_DIM / 32), 256, 0, stream>>>(w_h, H_DIM, G_DIM, whT_hi, whT_lo);
    split_transpose<<<dim3(X_DIM / 32, G_DIM / 32), 256, 0, stream>>>(w_i, X_DIM, G_DIM, wiT_hi, wiT_lo);

    for (int t0 = 0; t0 < T_DIM; t0 += chunk) {
        int nt = (T_DIM - t0 < chunk) ? (T_DIM - t0) : chunk;
        int rows = nt * B_DIM;
        embed_kernel<<<rows / 64, 256, 0, stream>>>(
            states + (size_t)t0 * B_DIM * S_DIMS,
            actions + (size_t)t0 * B_DIM * A_DIMS,
            rewards + (size_t)t0 * B_DIM,
            Ws, bs, Wa, ba, Wr, br, x_hi, x_lo);
        dim3 ggrid(G_DIM / 128, rows / 128);
        gates_mfma<<<ggrid, 256, 0, stream>>>(x_hi, x_lo, wiT_hi, wiT_lo, bgru, gx);

        const float* gx_c = gx;
        const unsigned short *whh = whT_hi, *whl = whT_lo;
        float* out_c = out;
        unsigned short *hhi = h_hi, *hlo = h_lo, *rhi = rh_hi, *rlo = rh_lo;
        float* zb = zbuf;
        unsigned* bar_c = bar;
        int nt_c = nt, t0_c = t0;
        void* kargs[] = {(void*)&gx_c, (void*)&nt_c, (void*)&t0_c,
                         (void*)&whh, (void*)&whl, (void*)&out_c,
                         (void*)&hhi, (void*)&hlo, (void*)&rhi, (void*)&rlo,
                         (void*)&zb, (void*)&bar_c};
        hipLaunchCooperativeKernel((void*)gru_persist, dim3(256), dim3(512),
                                   kargs, 0, stream);
    }
}

// Round 13
// 7969.061 us; speedup vs baseline: 3.1901x; 1.4246x over previous
//
#include <hip/hip_runtime.h>

#define T_DIM 512
#define B_DIM 256
#define S_DIMS 64
#define A_DIMS 16
#define E_DIM 128
#define H_DIM 512
#define X_DIM 384   // 3*E
#define G_DIM 1536  // 3*H
#define BAR_STRIDE 320   // uints per barrier instance: flags[256], release @256, pad

typedef __attribute__((ext_vector_type(8))) short short8;
typedef __attribute__((ext_vector_type(4))) float f32x4;
typedef __attribute__((ext_vector_type(2))) unsigned uint2v;
typedef __attribute__((ext_vector_type(4))) unsigned uint4v;

#define MFMA16(a, b, c) __builtin_amdgcn_mfma_f32_16x16x32_bf16(a, b, c, 0, 0, 0)

__device__ __forceinline__ float gelu_tanh(float x) {
    const float c = 0.7978845608028654f; // sqrt(2/pi)
    float x3 = x * x * x;
    return 0.5f * x * (1.0f + tanhf(c * (x + 0.044715f * x3)));
}

__device__ __forceinline__ float sigmoidf(float x) {
    return 1.0f / (1.0f + expf(-x));
}

// round-to-nearest-even fp32 -> bf16 (as ushort)
__device__ __forceinline__ unsigned short f2bf(float x) {
    unsigned u = __float_as_uint(x);
    u += 0x7FFFu + ((u >> 16) & 1u);
    return (unsigned short)(u >> 16);
}
__device__ __forceinline__ float bf2f(unsigned short b) {
    return __uint_as_float(((unsigned)b) << 16);
}

// ---- wide L2-bypass (coherent at Infinity Cache) accessors ----
__device__ __forceinline__ void stg_scf4(float* p, f32x4 v) {
    asm volatile("global_store_dwordx4 %0, %1, off sc0 sc1" :: "v"(p), "v"(v) : "memory");
}
__device__ __forceinline__ void stg_scu2(unsigned* p, uint2v v) {
    asm volatile("global_store_dwordx2 %0, %1, off sc0 sc1" :: "v"(p), "v"(v) : "memory");
}

// Flag barrier: no atomic RMWs. Each block stores flags[bid]=1; block 0 wave 0
// polls all 256 flags (one dwordx4/lane), sets release; all others poll release.
// Region (BAR_STRIDE uints) pre-zeroed per launch, used once.
__device__ __forceinline__ void gbar(unsigned* b) {
    asm volatile("s_waitcnt vmcnt(0) lgkmcnt(0)" ::: "memory");
    __syncthreads();
    const int tid = threadIdx.x;
    if (tid == 0) {
        unsigned one = 1u;
        asm volatile("global_store_dword %0, %1, off sc0 sc1"
                     :: "v"(b + blockIdx.x), "v"(one) : "memory");
    }
    if (blockIdx.x == 0) {
        if (tid < 64) {
            bool done;
            do {
                uint4v f;
                asm volatile("global_load_dwordx4 %0, %1, off sc0 sc1\n\ts_waitcnt vmcnt(0)"
                             : "=v"(f) : "v"(b + tid * 4));
                done = (f.x & f.y & f.z & f.w) != 0u;
            } while (!__all(done));
            if (tid == 0) {
                unsigned one = 1u;
                asm volatile("global_store_dword %0, %1, off sc0 sc1"
                             :: "v"(b + 256), "v"(one) : "memory");
            }
        }
    } else if (tid == 0) {
        unsigned r;
        do {
            __builtin_amdgcn_s_sleep(1);
            asm volatile("global_load_dword %0, %1, off sc0 sc1\n\ts_waitcnt vmcnt(0)"
                         : "=v"(r) : "v"(b + 256));
        } while (r == 0u);
    }
    __syncthreads();
    __builtin_amdgcn_sched_barrier(0);
}

// ---- split-bf16 MFMA chains: A-operand sc loads, weights in registers ----
#define ISSUE_A(k) do {                                                                            \
    asm volatile("global_load_dwordx4 %0, %1, off sc0 sc1" : "=v"(fah[k]) : "v"(pah + (k) * 32)); \
    asm volatile("global_load_dwordx4 %0, %1, off sc0 sc1" : "=v"(fal[k]) : "v"(pal + (k) * 32)); \
} while (0)

#define ASTEP(k, n) do {                                   \
    asm volatile("s_waitcnt vmcnt(" #n ")" ::: "memory");  \
    __builtin_amdgcn_sched_barrier(0);                     \
    a0 = MFMA16(fah[k], wAh[k], a0);                       \
    a1 = MFMA16(fah[k], wAl[k], a1);                       \
    a2 = MFMA16(fal[k], wAh[k], a2);                       \
} while (0)

#define BSTEP(k, n) do {                                   \
    asm volatile("s_waitcnt vmcnt(" #n ")" ::: "memory");  \
    __builtin_amdgcn_sched_barrier(0);                     \
    b0 = MFMA16(fah[k], wBh[k], b0);                       \
    b1 = MFMA16(fah[k], wBl[k], b1);                       \
    b2 = MFMA16(fal[k], wBh[k], b2);                       \
} while (0)

// ---------------- one-time: W[k][n] fp32 -> W^T[n][k] bf16 hi/lo
__global__ __launch_bounds__(256) void split_transpose(
    const float* __restrict__ w, int K, int N,
    unsigned short* __restrict__ t_hi, unsigned short* __restrict__ t_lo)
{
    __shared__ float tile[32][33];
    int k0 = blockIdx.x * 32, n0 = blockIdx.y * 32;
    int tid = threadIdx.x;
    #pragma unroll
    for (int p = 0; p < 4; ++p) {
        int i = tid + p * 256; int r = i >> 5, c = i & 31;
        tile[r][c] = w[(size_t)(k0 + r) * N + n0 + c];
    }
    __syncthreads();
    #pragma unroll
    for (int p = 0; p < 4; ++p) {
        int i = tid + p * 256; int r = i >> 5, c = i & 31;
        float v = tile[c][r];
        unsigned short hi = f2bf(v);
        size_t o = (size_t)(n0 + r) * K + k0 + c;
        t_hi[o] = hi;
        t_lo[o] = f2bf(v - bf2f(hi));
    }
}

// ---------------- Embedding (writes x as bf16 hi/lo, [rows][384])
__global__ __launch_bounds__(256) void embed_kernel(
    const float* __restrict__ s, const float* __restrict__ a, const float* __restrict__ r,
    const float* __restrict__ Ws, const float* __restrict__ bs,
    const float* __restrict__ Wa, const float* __restrict__ ba,
    const float* __restrict__ Wr, const float* __restrict__ br,
    unsigned short* __restrict__ x_hi, unsigned short* __restrict__ x_lo)
{
    __shared__ float Ws_s[64][128];
    __shared__ float Wa_s[16][128];
    __shared__ float Wr_s[128], bs_s[128], ba_s[128], br_s[128];
    __shared__ float s_s[64][64];
    __shared__ float a_s[64][16];
    __shared__ float r_s[64];
    int tid = threadIdx.x;
    for (int i = tid; i < 64 * 128; i += 256) Ws_s[i >> 7][i & 127] = Ws[i];
    for (int i = tid; i < 16 * 128; i += 256) Wa_s[i >> 7][i & 127] = Wa[i];
    if (tid < 128) { Wr_s[tid] = Wr[tid]; bs_s[tid] = bs[tid]; ba_s[tid] = ba[tid]; br_s[tid] = br[tid]; }
    size_t row0 = (size_t)blockIdx.x * 64;
    for (int i = tid; i < 64 * 64; i += 256) s_s[i >> 6][i & 63] = s[row0 * 64 + i];
    for (int i = tid; i < 64 * 16; i += 256) a_s[i >> 4][i & 15] = a[row0 * 16 + i];
    if (tid < 64) r_s[tid] = r[row0 + tid];
    __syncthreads();
    int e = tid & 127, ty = tid >> 7;
    for (int rw = ty; rw < 64; rw += 2) {
        float accS = bs_s[e];
        #pragma unroll
        for (int k = 0; k < 64; ++k) accS += s_s[rw][k] * Ws_s[k][e];
        float accA = ba_s[e];
        #pragma unroll
        for (int k = 0; k < 16; ++k) accA += a_s[rw][k] * Wa_s[k][e];
        float accR = br_s[e] + r_s[rw] * Wr_s[e];
        float v0 = gelu_tanh(accS);
        float v1 = gelu_tanh(accA);
        float v2 = gelu_tanh(accR);
        size_t base = (row0 + rw) * X_DIM;
        unsigned short h0 = f2bf(v0), h1 = f2bf(v1), h2 = f2bf(v2);
        x_hi[base + e] = h0;        x_lo[base + e] = f2bf(v0 - bf2f(h0));
        x_hi[base + 128 + e] = h1;  x_lo[base + 128 + e] = f2bf(v1 - bf2f(h1));
        x_hi[base + 256 + e] = h2;  x_lo[base + 256 + e] = f2bf(v2 - bf2f(h2));
    }
}

// ---------------- Gates GEMM (MFMA): gx[m][n] = x[m][:] . wiT[n][:] + bias[n]
__global__ __launch_bounds__(256) void gates_mfma(
    const unsigned short* __restrict__ x_hi, const unsigned short* __restrict__ x_lo,
    const unsigned short* __restrict__ wiT_hi, const unsigned short* __restrict__ wiT_lo,
    const float* __restrict__ bias, float* __restrict__ C)
{
    const int tid = threadIdx.x;
    const int lane = tid & 63;
    const int wv = tid >> 6;
    const int wm = wv >> 1, wn = wv & 1;
    const size_t m0 = (size_t)blockIdx.y * 128 + wm * 64;
    const int n0 = blockIdx.x * 128 + wn * 64;
    const int lr = lane & 15, lk = (lane >> 4) * 8;
    f32x4 acc[4][4] = {};
    for (int k0 = 0; k0 < X_DIM; k0 += 32) {
        short8 ahi[4], alo[4], bhi[4], blo[4];
        #pragma unroll
        for (int i = 0; i < 4; ++i) {
            size_t oa = (m0 + i * 16 + lr) * X_DIM + k0 + lk;
            ahi[i] = *reinterpret_cast<const short8*>(&x_hi[oa]);
            alo[i] = *reinterpret_cast<const short8*>(&x_lo[oa]);
            size_t ob = (size_t)(n0 + i * 16 + lr) * X_DIM + k0 + lk;
            bhi[i] = *reinterpret_cast<const short8*>(&wiT_hi[ob]);
            blo[i] = *reinterpret_cast<const short8*>(&wiT_lo[ob]);
        }
        #pragma unroll
        for (int i = 0; i < 4; ++i)
            #pragma unroll
            for (int j = 0; j < 4; ++j) {
                acc[i][j] = MFMA16(ahi[i], bhi[j], acc[i][j]);
                acc[i][j] = MFMA16(ahi[i], blo[j], acc[i][j]);
                acc[i][j] = MFMA16(alo[i], bhi[j], acc[i][j]);
            }
    }
    const int rbase = (lane >> 4) * 4;
    #pragma unroll
    for (int i = 0; i < 4; ++i)
        #pragma unroll
        for (int j = 0; j < 4; ++j) {
            int colg = n0 + j * 16 + lr;
            float b = bias[colg];
            #pragma unroll
            for (int r = 0; r < 4; ++r) {
                size_t row = m0 + i * 16 + rbase + r;
                C[row * G_DIM + colg] = acc[i][j][r] + b;
            }
        }
}

// ---------------- Persistent GRU: nt steps, 2 flag barriers/step.
// Weights held in VGPRs for the whole launch; h/rh/z via sc0sc1 (MALL-coherent).
__global__ __launch_bounds__(512, 2) void gru_persist(
    const float* __restrict__ gx,    // nt x B x G
    int nt, int t0,
    const unsigned short* __restrict__ whT_hi, const unsigned short* __restrict__ whT_lo,
    float* __restrict__ out,         // T x B x H
    unsigned short* __restrict__ h_hi, unsigned short* __restrict__ h_lo,
    unsigned short* __restrict__ rh_hi, unsigned short* __restrict__ rh_lo,
    float* __restrict__ zbuf,
    unsigned* __restrict__ bar)
{
    __shared__ float sbuf[2560];         // [0,1536): k-reduction; [1536,2560): C tile
    const int CB = 1536;
    const int tid = threadIdx.x;
    const int bid = blockIdx.x;
    const int w = tid >> 6;
    const int lane = tid & 63;
    const int lr = lane & 15;
    const int lk = (lane >> 4) * 8;
    const int rbase = (lane >> 4) * 4;

    // phase A geometry: (mg 8) x (ng 32) blocks; 8 waves = 2m x 2n tiles x 2 k-halves
    const int mgA = bid >> 5, ngA = bid & 31;
    const int halfA = w >> 2, widxA = w & 3;
    const int mtA = widxA >> 1, ntA = widxA & 1;
    const int arowA = mgA * 32 + mtA * 16 + lr;
    const int browA = ngA * 32 + ntA * 16 + lr;
    const int kbA = halfA * 256 + lk;
    // phase A epilogue coords
    const int erowlA = tid >> 3, ec4A = (tid & 7) * 4;
    const int erowA = mgA * 32 + erowlA;
    const int ecolA = ngA * 32 + ec4A;

    // phase B geometry: 512 tiles (16m x 32n of 16x16); block does 2 tiles x 4 k-quarters
    const int tlB = bid * 2 + (w >> 2);
    const int qB = w & 3;
    const int slotB = w >> 2;
    const int m0B = (tlB >> 5) * 16;
    const int n0B = (tlB & 31) * 16;
    const int arowB = m0B + lr;
    const int browB = 1024 + n0B + lr;
    const int kbB = qB * 128 + lk;
    // phase B epilogue coords
    const int etlB = tid >> 6;
    const int erowlB = (tid >> 2) & 15;
    const int ec4B = (tid & 3) * 4;
    const int etlgB = bid * 2 + etlB;
    const int erowB = (etlgB >> 5) * 16 + erowlB;
    const int ecolB = (etlgB & 31) * 16 + ec4B;

    // ---- preload this wave's weight fragments into registers (held all steps)
    short8 wAh[8], wAl[8], wBh[4], wBl[4];
    {
        const unsigned short* ph = whT_hi + (size_t)browA * H_DIM + kbA;
        const unsigned short* pl = whT_lo + (size_t)browA * H_DIM + kbA;
        #pragma unroll
        for (int k = 0; k < 8; ++k) {
            wAh[k] = *reinterpret_cast<const short8*>(ph + k * 32);
            wAl[k] = *reinterpret_cast<const short8*>(pl + k * 32);
        }
        const unsigned short* ph2 = whT_hi + (size_t)browB * H_DIM + kbB;
        const unsigned short* pl2 = whT_lo + (size_t)browB * H_DIM + kbB;
        #pragma unroll
        for (int k = 0; k < 4; ++k) {
            wBh[k] = *reinterpret_cast<const short8*>(ph2 + k * 32);
            wBl[k] = *reinterpret_cast<const short8*>(pl2 + k * 32);
        }
    }

    for (int s = 0; s < nt; ++s) {
        const int t = t0 + s;
        const float* gxs = gx + (size_t)s * B_DIM * G_DIM;
        const float* hpf = out + (size_t)(t - 1) * B_DIM * H_DIM; // valid iff t>0
        float* out_t = out + (size_t)t * B_DIM * H_DIM;

        // ---- step-start prefetch (gx for both phases; h_prev for epilogues) ----
        f32x4 gA = {}, gB = {}, hpA = {}, hpB = {};
        if (tid < 256) {
            asm volatile("global_load_dwordx4 %0, %1, off"
                         : "=v"(gA) : "v"(gxs + (size_t)erowA * G_DIM + ecolA));
            if (t > 0 && ngA >= 16)
                asm volatile("global_load_dwordx4 %0, %1, off"
                             : "=v"(hpA) : "v"(hpf + (size_t)erowA * H_DIM + (ecolA - H_DIM)));
        }
        if (tid < 128) {
            asm volatile("global_load_dwordx4 %0, %1, off"
                         : "=v"(gB) : "v"(gxs + (size_t)erowB * G_DIM + 1024 + ecolB));
            if (t > 0)
                asm volatile("global_load_dwordx4 %0, %1, off"
                             : "=v"(hpB) : "v"(hpf + (size_t)erowB * H_DIM + ecolB));
        }

        // ================= phase A: zr = sigmoid(gx_zr + h @ Wzr) =================
        f32x4 acc = {};
        if (t > 0) {
            const unsigned short* pah = h_hi + (size_t)arowA * H_DIM + kbA;
            const unsigned short* pal = h_lo + (size_t)arowA * H_DIM + kbA;
            short8 fah[8], fal[8];
            f32x4 a0 = {}, a1 = {}, a2 = {};
            ISSUE_A(0); ISSUE_A(1); ISSUE_A(2); ISSUE_A(3);
            ISSUE_A(4); ISSUE_A(5); ISSUE_A(6); ISSUE_A(7);
            ASTEP(0, 14); ASTEP(1, 12); ASTEP(2, 10); ASTEP(3, 8);
            ASTEP(4, 6);  ASTEP(5, 4);  ASTEP(6, 2);  ASTEP(7, 0);
            acc = a0 + a1;
            acc = acc + a2;
        }
        if (halfA == 1) {
            #pragma unroll
            for (int j = 0; j < 4; ++j) sbuf[widxA * 256 + lane * 4 + j] = acc[j];
        }
        __syncthreads();
        if (halfA == 0) {
            #pragma unroll
            for (int j = 0; j < 4; ++j) acc[j] += sbuf[widxA * 256 + lane * 4 + j];
            #pragma unroll
            for (int r = 0; r < 4; ++r)
                sbuf[CB + (mtA * 16 + rbase + r) * 32 + ntA * 16 + lr] = acc[r];
        }
        __syncthreads();
        if (tid < 256) {
            asm volatile("s_waitcnt vmcnt(0)" ::: "memory");
            __builtin_amdgcn_sched_barrier(0);
            f32x4 v;
            #pragma unroll
            for (int j = 0; j < 4; ++j)
                v[j] = sigmoidf(gA[j] + sbuf[CB + erowlA * 32 + ec4A + j]);
            if (ngA < 16) {
                stg_scf4(zbuf + (size_t)erowA * H_DIM + ecolA, v);
            } else {
                int c = ecolA - H_DIM;
                f32x4 rh;
                #pragma unroll
                for (int j = 0; j < 4; ++j) rh[j] = v[j] * hpA[j];
                unsigned short e0 = f2bf(rh[0]), e1 = f2bf(rh[1]), e2 = f2bf(rh[2]), e3 = f2bf(rh[3]);
                uint2v uh = { (unsigned)e0 | ((unsigned)e1 << 16), (unsigned)e2 | ((unsigned)e3 << 16) };
                stg_scu2((unsigned*)(rh_hi + (size_t)erowA * H_DIM + c), uh);
                unsigned short l0 = f2bf(rh[0] - bf2f(e0)), l1 = f2bf(rh[1] - bf2f(e1));
                unsigned short l2 = f2bf(rh[2] - bf2f(e2)), l3 = f2bf(rh[3] - bf2f(e3));
                uint2v ul = { (unsigned)l0 | ((unsigned)l1 << 16), (unsigned)l2 | ((unsigned)l3 << 16) };
                stg_scu2((unsigned*)(rh_lo + (size_t)erowA * H_DIM + c), ul);
            }
        }
        gbar(bar + (size_t)(2 * t) * BAR_STRIDE);

        // ================= phase B: a = tanh(gx_a + rh @ Wa); h = hp + z*(a-hp) ====
        f32x4 accB;
        f32x4 zvB = {};
        {
            const unsigned short* pah = rh_hi + (size_t)arowB * H_DIM + kbB;
            const unsigned short* pal = rh_lo + (size_t)arowB * H_DIM + kbB;
            short8 fah[4], fal[4];
            f32x4 b0 = {}, b1 = {}, b2 = {};
            ISSUE_A(0); ISSUE_A(1); ISSUE_A(2); ISSUE_A(3);
            if (tid < 128)
                asm volatile("global_load_dwordx4 %0, %1, off sc0 sc1"
                             : "=v"(zvB) : "v"(zbuf + (size_t)erowB * H_DIM + ecolB));
            BSTEP(0, 6); BSTEP(1, 4); BSTEP(2, 2); BSTEP(3, 0);
            accB = b0 + b1;
            accB = accB + b2;
        }
        if (qB > 0) {
            int base = (slotB * 3 + (qB - 1)) * 256;
            #pragma unroll
            for (int j = 0; j < 4; ++j) sbuf[base + lane * 4 + j] = accB[j];
        }
        __syncthreads();
        if (qB == 0) {
            #pragma unroll
            for (int p = 0; p < 3; ++p) {
                int base = (slotB * 3 + p) * 256;
                #pragma unroll
                for (int j = 0; j < 4; ++j) accB[j] += sbuf[base + lane * 4 + j];
            }
            #pragma unroll
            for (int r = 0; r < 4; ++r)
                sbuf[CB + slotB * 256 + (rbase + r) * 16 + lr] = accB[r];
        }
        __syncthreads();
        if (tid < 128) {
            asm volatile("s_waitcnt vmcnt(0)" ::: "memory");
            __builtin_amdgcn_sched_barrier(0);
            f32x4 hnew;
            #pragma unroll
            for (int j = 0; j < 4; ++j) {
                float av = tanhf(gB[j] + sbuf[CB + etlB * 256 + erowlB * 16 + ec4B + j]);
                hnew[j] = hpB[j] + zvB[j] * (av - hpB[j]);
            }
            stg_scf4(out_t + (size_t)erowB * H_DIM + ecolB, hnew);
            unsigned short e0 = f2bf(hnew[0]), e1 = f2bf(hnew[1]), e2 = f2bf(hnew[2]), e3 = f2bf(hnew[3]);
            uint2v uh = { (unsigned)e0 | ((unsigned)e1 << 16), (unsigned)e2 | ((unsigned)e3 << 16) };
            stg_scu2((unsigned*)(h_hi + (size_t)erowB * H_DIM + ecolB), uh);
            unsigned short l0 = f2bf(hnew[0] - bf2f(e0)), l1 = f2bf(hnew[1] - bf2f(e1));
            unsigned short l2 = f2bf(hnew[2] - bf2f(e2)), l3 = f2bf(hnew[3] - bf2f(e3));
            uint2v ul = { (unsigned)l0 | ((unsigned)l1 << 16), (unsigned)l2 | ((unsigned)l3 << 16) };
            stg_scu2((unsigned*)(h_lo + (size_t)erowB * H_DIM + ecolB), ul);
        }
        gbar(bar + (size_t)(2 * t + 1) * BAR_STRIDE);
    }
}

extern "C" void kernel_launch(void* const* d_in, const int* in_sizes, int n_in,
                              void* d_out, int out_size, void* d_ws, size_t ws_size,
                              hipStream_t stream) {
    const float* states  = (const float*)d_in[0];
    const float* actions = (const float*)d_in[1];
    const float* rewards = (const float*)d_in[2];
    const float* Ws   = (const float*)d_in[3];
    const float* bs   = (const float*)d_in[4];
    const float* Wa   = (const float*)d_in[5];
    const float* ba   = (const float*)d_in[6];
    const float* Wr   = (const float*)d_in[7];
    const float* br   = (const float*)d_in[8];
    const float* w_i  = (const float*)d_in[9];
    const float* w_h  = (const float*)d_in[10];
    const float* bgru = (const float*)d_in[11];
    float* out = (float*)d_out;

    // ---- workspace carve-up
    char* p = (char*)d_ws;
    unsigned short* whT_hi = (unsigned short*)p; p += (size_t)G_DIM * H_DIM * 2;
    unsigned short* whT_lo = (unsigned short*)p; p += (size_t)G_DIM * H_DIM * 2;
    unsigned short* wiT_hi = (unsigned short*)p; p += (size_t)G_DIM * X_DIM * 2;
    unsigned short* wiT_lo = (unsigned short*)p; p += (size_t)G_DIM * X_DIM * 2;
    float*          zbuf   = (float*)p;          p += (size_t)B_DIM * H_DIM * 4;
    unsigned short* rh_hi  = (unsigned short*)p; p += (size_t)B_DIM * H_DIM * 2;
    unsigned short* rh_lo  = (unsigned short*)p; p += (size_t)B_DIM * H_DIM * 2;
    unsigned short* h_hi   = (unsigned short*)p; p += (size_t)B_DIM * H_DIM * 2;
    unsigned short* h_lo   = (unsigned short*)p; p += (size_t)B_DIM * H_DIM * 2;
    unsigned*       bar    = (unsigned*)p;       p += (size_t)2 * T_DIM * BAR_STRIDE * sizeof(unsigned);
    size_t fixed = (size_t)(p - (char*)d_ws);
    size_t per_step = (size_t)B_DIM * G_DIM * 4 + (size_t)B_DIM * X_DIM * 2 * 2;
    int chunk = (int)((ws_size > fixed ? ws_size - fixed : 0) / per_step);
    if (chunk > T_DIM) chunk = T_DIM;
    if (chunk < 1) chunk = 1;
    float* gx = (float*)p;
    unsigned short* x_hi = (unsigned short*)((char*)gx + (size_t)chunk * B_DIM * G_DIM * 4);
    unsigned short* x_lo = x_hi + (size_t)chunk * B_DIM * X_DIM;

    // barrier flags must start at 0 on every call (graph replays included)
    hipMemsetAsync(bar, 0, (size_t)2 * T_DIM * BAR_STRIDE * sizeof(unsigned), stream);

    // ---- one-time weight split/transpose
    split_transpose<<<dim3(H_DIM / 32, G_DIM / 32), 256, 0, stream>>>(w_h, H_DIM, G_DIM, whT_hi, whT_lo);
    split_transpose<<<dim3(X_DIM / 32, G_DIM / 32), 256, 0, stream>>>(w_i, X_DIM, G_DIM, wiT_hi, wiT_lo);

    for (int t0 = 0; t0 < T_DIM; t0 += chunk) {
        int nt = (T_DIM - t0 < chunk) ? (T_DIM - t0) : chunk;
        int rows = nt * B_DIM;
        embed_kernel<<<rows / 64, 256, 0, stream>>>(
            states + (size_t)t0 * B_DIM * S_DIMS,
            actions + (size_t)t0 * B_DIM * A_DIMS,
            rewards + (size_t)t0 * B_DIM,
            Ws, bs, Wa, ba, Wr, br, x_hi, x_lo);
        dim3 ggrid(G_DIM / 128, rows / 128);
        gates_mfma<<<ggrid, 256, 0, stream>>>(x_hi, x_lo, wiT_hi, wiT_lo, bgru, gx);

        const float* gx_c = gx;
        const unsigned short *whh = whT_hi, *whl = whT_lo;
        float* out_c = out;
        unsigned short *hhi = h_hi, *hlo = h_lo, *rhi = rh_hi, *rlo = rh_lo;
        float* zb = zbuf;
        unsigned* bar_c = bar;
        int nt_c = nt, t0_c = t0;
        void* kargs[] = {(void*)&gx_c, (void*)&nt_c, (void*)&t0_c,
                         (void*)&whh, (void*)&whl, (void*)&out_c,
                         (void*)&hhi, (void*)&hlo, (void*)&rhi, (void*)&rlo,
                         (void*)&zb, (void*)&bar_c};
        hipLaunchCooperativeKernel((void*)gru_persist, dim3(256), dim3(512),
                                   kargs, 0, stream);
    }
}